// Round 13
// baseline (1340.056 us; speedup 1.0000x reference)
//
#include <hip/hip_runtime.h>

// LSTM predictor: B=2048 rows, T=2048 + 128 future, H=51.
// ONE WAVE per batch row (grid 2048 x 64), barrier-free. r12 base:
// f16 weight pairs pre-scaled by log2e, x folded into dot pair 25,
// fc head rides lane 52's a0-chain, no fc LDS.
// r12 lesson: flat wall + lower VALUBusy after issue trims => latency-bound
// margin. This round: (1) 8 accumulator chains (13-deep instead of 26-deep
// dot dependency), (2) h-broadcast software-pipelined: the 7 ds_read_b128
// for step t+1 issue right after step t's ds_write, hiding LDS latency
// under the output tail + loop overhead.

typedef _Float16 v2h __attribute__((ext_vector_type(2)));
typedef float    v4f __attribute__((ext_vector_type(4)));

constexpr int Hh = 51;

__device__ __forceinline__ float fexp2(float x){ return __builtin_amdgcn_exp2f(x); }
__device__ __forceinline__ float frcp(float x) { return __builtin_amdgcn_rcpf(x); }
// inputs pre-scaled by log2e
__device__ __forceinline__ float sigm_p(float a){ return frcp(1.f + fexp2(-a)); }
__device__ __forceinline__ float tanh_p(float a){ return 1.f - 2.f * frcp(1.f + fexp2(a + a)); }
__device__ __forceinline__ float tanh_c(float x){ return 1.f - 2.f * frcp(1.f + fexp2(2.88539008f * x)); }

__device__ __forceinline__ float rdlane(float v, int lane){
  return __int_as_float(__builtin_amdgcn_readlane(__float_as_int(v), lane));
}

__device__ __forceinline__ v2h bch(float f){
  union { float f; v2h h; } u; u.f = f; return u.h;
}
__device__ __forceinline__ v2h ovr_hi(float f, unsigned hi16){
  unsigned u = (__float_as_uint(f) & 0xFFFFu) | (hi16 << 16);
  union { unsigned u; v2h h; } c; c.u = u; return c.h;
}

__device__ __forceinline__ float dot2(v2h a, v2h b, float c){
  return __builtin_amdgcn_fdot2(a, b, c, false);
}

__global__ __launch_bounds__(64)
__attribute__((amdgpu_waves_per_eu(1)))
void lstm_kernel(const float* __restrict__ x,
                 const float* __restrict__ W_ih,
                 const float* __restrict__ W_hh,
                 const float* __restrict__ b_ih,
                 const float* __restrict__ b_hh,
                 const float* __restrict__ fc_w,
                 const float* __restrict__ fc_b,
                 float* __restrict__ out,
                 int T, int OT)
{
  const int k   = threadIdx.x;   // lane = hidden unit (52 = fc lane)
  const int row = blockIdx.x;    // batch row
  const float S = 1.44269504089f;  // log2(e)

  __shared__ __align__(16) _Float16 hbuf16[64];  // h; slot 51+ junk (x overridden in-reg)

  hbuf16[k] = (_Float16)0.f;

  // ---- weights: 4 gate rows per lane as f16 pairs, pre-scaled by log2e.
  // pair 25 = (w50*s, wi*s) -- x folded into the dot stream.
  const int kc = (k < Hh) ? k : (Hh - 1);        // clamp, no divergence
  v2h w0[26], w1[26], w2[26], w3[26];
  const long r0 = (long)(0 * Hh + kc) * Hh;
  const long r1 = (long)(1 * Hh + kc) * Hh;
  const long r2 = (long)(2 * Hh + kc) * Hh;
  const long r3 = (long)(3 * Hh + kc) * Hh;
#pragma unroll
  for (int m = 0; m < 25; ++m) {
    w0[m] = (v2h){(_Float16)(S*W_hh[r0 + 2*m]), (_Float16)(S*W_hh[r0 + 2*m + 1])};
    w1[m] = (v2h){(_Float16)(S*W_hh[r1 + 2*m]), (_Float16)(S*W_hh[r1 + 2*m + 1])};
    w2[m] = (v2h){(_Float16)(S*W_hh[r2 + 2*m]), (_Float16)(S*W_hh[r2 + 2*m + 1])};
    w3[m] = (v2h){(_Float16)(S*W_hh[r3 + 2*m]), (_Float16)(S*W_hh[r3 + 2*m + 1])};
  }
  w0[25] = (v2h){(_Float16)(S*W_hh[r0 + 50]), (_Float16)(S*W_ih[0*Hh + kc])};
  w1[25] = (v2h){(_Float16)(S*W_hh[r1 + 50]), (_Float16)(S*W_ih[1*Hh + kc])};
  w2[25] = (v2h){(_Float16)(S*W_hh[r2 + 50]), (_Float16)(S*W_ih[2*Hh + kc])};
  w3[25] = (v2h){(_Float16)(S*W_hh[r3 + 50]), (_Float16)(S*W_ih[3*Hh + kc])};
  float bs0 = S*(b_ih[0*Hh + kc] + b_hh[0*Hh + kc]);
  const float bs1 = S*(b_ih[1*Hh + kc] + b_hh[1*Hh + kc]);
  const float bs2 = S*(b_ih[2*Hh + kc] + b_hh[2*Hh + kc]);
  const float bs3 = S*(b_ih[3*Hh + kc] + b_hh[3*Hh + kc]);
  const float fcw = (k < Hh) ? fc_w[k] : 0.f;    // f32 head weights (butterfly tail)
  const float fcb = fc_b[0];

  if (k == 52) {                                 // fc lane: a0-chain = out(t-1)
#pragma unroll
    for (int m = 0; m < 25; ++m)
      w0[m] = (v2h){(_Float16)fc_w[2*m], (_Float16)fc_w[2*m + 1]};
    w0[25] = (v2h){(_Float16)fc_w[50], (_Float16)0.f};
    bs0 = fcb;
  }

  float c = 0.f, h = 0.f;

  // ---- software-pipelined h broadcast: hv[] holds this step's h words
  const v4f* hb4 = (const v4f*)hbuf16;
  v4f hv[7];
  asm volatile("" ::: "memory");
#pragma unroll
  for (int q = 0; q < 7; ++q) hv[q] = hb4[q];

  // cell: one LSTM step; xu16 = f16 bits of x_t. Returns pre-activation A0
  // (lane 52's value = out(t-1)). 8 accumulator chains, 13-deep each.
  auto cell = [&](unsigned xu16) -> float {
    float a0 = bs0, a1 = bs1, a2 = bs2, a3 = bs3;   // even pairs
    float e0 = 0.f, e1 = 0.f, e2 = 0.f, e3 = 0.f;   // odd pairs
#pragma unroll
    for (int q = 0; q < 7; ++q) {
      const v4f hq = hv[q];
      const int p = 4 * q;
      const v2h h0 = bch(hq.x);
      const v2h h1 = (q == 6) ? ovr_hi(hq.y, xu16) : bch(hq.y);  // x-inject
      a0 = dot2(w0[p], h0, a0); a1 = dot2(w1[p], h0, a1);
      a2 = dot2(w2[p], h0, a2); a3 = dot2(w3[p], h0, a3);
      e0 = dot2(w0[p+1], h1, e0); e1 = dot2(w1[p+1], h1, e1);
      e2 = dot2(w2[p+1], h1, e2); e3 = dot2(w3[p+1], h1, e3);
      if (q < 6) {
        const v2h h2 = bch(hq.z), h3 = bch(hq.w);
        a0 = dot2(w0[p+2], h2, a0); a1 = dot2(w1[p+2], h2, a1);
        a2 = dot2(w2[p+2], h2, a2); a3 = dot2(w3[p+2], h2, a3);
        e0 = dot2(w0[p+3], h3, e0); e1 = dot2(w1[p+3], h3, e1);
        e2 = dot2(w2[p+3], h3, e2); e3 = dot2(w3[p+3], h3, e3);
      }
    }
    const float A0 = a0 + e0, A1 = a1 + e1, A2 = a2 + e2, A3 = a3 + e3;
    const float ia = sigm_p(A0);
    const float fa = sigm_p(A1);
    const float ga = tanh_p(A2);
    const float oa = sigm_p(A3);
    c = fmaf(fa, c, ia * ga);
    h = oa * tanh_c(c);
    asm volatile("" ::: "memory");
    hbuf16[k] = (_Float16)h;               // publish (same-wave DS FIFO order)
    asm volatile("" ::: "memory");
#pragma unroll
    for (int q = 0; q < 7; ++q) hv[q] = hb4[q];   // prefetch next step's h
    return A0;
  };

  float obuf = 0.f;

  // ---- main phase: T steps in chunks of 64; fc output emitted one step late
  for (int tc = 0; tc < T; tc += 64) {
    const float xv = x[(long)row * T + tc + k];            // coalesced chunk load
    const unsigned xhu =
        (unsigned)__builtin_bit_cast(unsigned short, (_Float16)xv);
#pragma unroll 1
    for (int i = 0; i < 64; ++i) {
      const int t = tc + i;
      const unsigned xu = (unsigned)__builtin_amdgcn_readlane((int)xhu, i);
      const float a0v = cell(xu);
      const float o = rdlane(a0v, 52);                     // out(t-1)
      if (t > 0) {
        obuf = (k == ((t - 1) & 63)) ? o : obuf;
        if (((t - 1) & 63) == 63)                          // chunk complete
          out[(long)row * OT + (t - 64) + k] = obuf;       // coalesced
      }
    }
  }

  // ---- emit out(T-1) (needs h(T-1), not yet through the dots)
  float p = h * fcw;
#pragma unroll
  for (int off = 32; off > 0; off >>= 1) p += __shfl_xor(p, off, 64);
  float out_prev = p + fcb;
  obuf = (k == 63) ? out_prev : obuf;
  out[(long)row * OT + (T - 64) + k] = obuf;               // last main chunk

  // ---- future phase: feedback out -> x, butterfly each step
  for (int t = T; t < OT; ++t) {
    const unsigned xu =
        (unsigned)__builtin_bit_cast(unsigned short, (_Float16)out_prev);
    cell(xu);
    float q = h * fcw;
#pragma unroll
    for (int off = 32; off > 0; off >>= 1) q += __shfl_xor(q, off, 64);
    const float out_t = q + fcb;
    obuf = (k == (t & 63)) ? out_t : obuf;
    if ((t & 63) == 63)
      out[(long)row * OT + (t - 63) + k] = obuf;           // coalesced
    out_prev = out_t;
  }
}

extern "C" void kernel_launch(void* const* d_in, const int* in_sizes, int n_in,
                              void* d_out, int out_size, void* d_ws, size_t ws_size,
                              hipStream_t stream) {
  const float* x    = (const float*)d_in[0];
  const float* W_ih = (const float*)d_in[1];
  const float* W_hh = (const float*)d_in[2];
  const float* b_ih = (const float*)d_in[3];
  const float* b_hh = (const float*)d_in[4];
  const float* fc_w = (const float*)d_in[5];
  const float* fc_b = (const float*)d_in[6];
  float* out = (float*)d_out;

  const int B  = 2048;
  const int T  = in_sizes[0] / B;   // 2048
  const int OT = out_size / B;      // 2176

  lstm_kernel<<<dim3(B), dim3(64), 0, stream>>>(x, W_ih, W_hh, b_ih, b_hh,
                                                fc_w, fc_b, out, T, OT);
}